// Round 13
// baseline (162.348 us; speedup 1.0000x reference)
//
#include <hip/hip_runtime.h>
#include <math.h>

// Problem constants (match reference)
constexpr int cB = 2, cN = 8192, cS = 4096;
constexpr int cTR = 12;    // stored trans channels (0-5 before, 6-11 after)
constexpr int CAP = 96;    // survivor slots per query (serves both modes; mode-1 subset)

typedef unsigned long long ull;

// ---- exact distance: EXACTLY mirrors reference arithmetic ----
// ref: sq = (x*x + y*y) + z*z ; d2 = (sq_i + sq_j) - 2*dot ; d = sqrt(max(d2,1e-12))
__device__ __forceinline__ float d2exact_rn(float qx, float qy, float qz, float qw,
                                            float cx, float cy, float cz, float cw) {
  float dot = __fadd_rn(__fadd_rn(__fmul_rn(qx, cx), __fmul_rn(qy, cy)), __fmul_rn(qz, cz));
  return __fsub_rn(__fadd_rn(qw, cw), __fmul_rn(2.0f, dot));
}
__device__ __forceinline__ float dist_rn4(float4 a, float4 b) {
  return sqrtf(fmaxf(d2exact_rn(a.x, a.y, a.z, a.w, b.x, b.y, b.z, b.w), 1e-12f));
}
__device__ __forceinline__ void ce64(ull& a, ull& b) {
  ull lo = a < b ? a : b;
  ull hi = a < b ? b : a;
  a = lo; b = hi;
}
// wave-wide sorted top-4 of per-lane value v (all lanes end with identical a0..a3)
__device__ __forceinline__ void wave_top4(float v, float& o0, float& o1, float& o2, float& o3) {
  const float INF = __uint_as_float(0x7f800000u);
  float a0 = v, a1 = INF, a2 = INF, a3 = INF;
  #pragma unroll
  for (int off = 1; off < 64; off <<= 1) {
    float s0 = __shfl_xor(a0, off, 64), s1 = __shfl_xor(a1, off, 64);
    float s2 = __shfl_xor(a2, off, 64), s3 = __shfl_xor(a3, off, 64);
    float n0 = fminf(a0, s3), n1 = fminf(a1, s2), n2 = fminf(a2, s1), n3 = fminf(a3, s0);
    float t;
    t = fminf(n0, n2); n2 = fmaxf(n0, n2); n0 = t;
    t = fminf(n1, n3); n3 = fmaxf(n1, n3); n1 = t;
    t = fminf(n0, n1); n1 = fmaxf(n0, n1); n0 = t;
    t = fminf(n2, n3); n3 = fmaxf(n2, n3); n2 = t;
    a0 = n0; a1 = n1; a2 = n2; a3 = n3;
  }
  o0 = a0; o1 = a1; o2 = a2; o3 = a3;
}

// ---- K1: pack. P = orig order (clean sq); P2 = sampled-first permuted; idxMap -> orig ----
// smp sorted per batch: sampled rank lo via binary search; unsampled pos = cS + n - lo.
__global__ __launch_bounds__(512) void pack_kernel(const float* __restrict__ xyz,
                                                   const int* __restrict__ smp,
                                                   float4* __restrict__ P,
                                                   float4* __restrict__ P2,
                                                   int* __restrict__ idxMap,
                                                   float* __restrict__ oxyz) {
  int t = blockIdx.x * 512 + threadIdx.x;
  if (t < cB * cN) {
    int b = t >> 13, n = t & (cN - 1);
    const float* p = xyz + t * 3;
    float x = p[0], y = p[1], z = p[2];
    float sq = __fadd_rn(__fadd_rn(__fmul_rn(x, x), __fmul_rn(y, y)), __fmul_rn(z, z));
    const int* sb = smp + b * cS;
    int lo = 0, hi = cS;
    while (lo < hi) { int mid = (lo + hi) >> 1; if (sb[mid] < n) lo = mid + 1; else hi = mid; }
    bool flg = (lo < cS) && (sb[lo] == n);
    P[t] = make_float4(x, y, z, sq);
    int pos = flg ? lo : (cS + n - lo);
    int gp = b * cN + pos;
    P2[gp] = make_float4(x, y, z, sq);
    idxMap[gp] = n;
  } else if (t < cB * cN + cB * cS) {
    int j = t - cB * cN;
    int b = j >> 12;
    const float* p = xyz + (b * cN + smp[j]) * 3;
    oxyz[j * 3 + 0] = p[0]; oxyz[j * 3 + 1] = p[1]; oxyz[j * 3 + 2] = p[2];
  }
}

// ---- K2: 4-NN both modes, register-streamed candidates, POSITION-ONLY survivor push ----
// 2048 blocks x 256 thr; block owns 4 queries. Pass A: sampled region, per-lane fast minima;
// block-wide tau = exact 4th-smallest of 256 lane-minima (+MARGIN 2e-3 >> fast/exact gap).
// Pass B: fast gate -> push P2 position only (6-inst body; one buffer per query, mode
// derivable: pos < cS <=> sampled). Final stage: <=CAP survivors/query get exact
// reference-rounded d2 + u64 (d2bits, idx) keys (mode0: orig id; mode1: SP idx) ->
// butterfly select == reference top_k selection bit-identically.
__global__ __launch_bounds__(256, 4) void knn_kernel(const float4* __restrict__ P2,
                                                     const int* __restrict__ idxMap,
                                                     float* __restrict__ trans,
                                                     int* __restrict__ AB,
                                                     int* __restrict__ AA) {
  __shared__ int sPos[4][CAP];
  __shared__ int sCnt[4];
  __shared__ float tmpF[4][16];

  const int tid = threadIdx.x, wv = tid >> 6, lane = tid & 63;
  const int qbase = blockIdx.x * 4;        // 4 | 4096 -> same batch
  const int b = qbase >> 12;
  const int s0 = qbase & (cS - 1);
  const float4* Cb = P2 + b * cN;
  const int* im = idxMap + b * cN;
  const float INF = __uint_as_float(0x7f800000u);
  const float MARGIN = 2e-3f;

  float4 qf[4];   // fast coeffs (-2x,-2y,-2z,sq); exact coords: x = -0.5*qf.x
  #pragma unroll
  for (int qi = 0; qi < 4; qi++) {
    float4 q = Cb[s0 + qi];                // sampled-first: SP idx == P2 position
    qf[qi] = make_float4(-2.0f * q.x, -2.0f * q.y, -2.0f * q.z, q.w);
  }
  if (tid < 4) sCnt[tid] = 0;

  // ---- Pass A: sampled region (positions [0, cS)), per-lane fast minima ----
  float mn[4] = {INF, INF, INF, INF};
  #pragma unroll 4
  for (int k = 0; k < 16; k++) {
    float4 cp = Cb[k * 256 + tid];
    #pragma unroll
    for (int qi = 0; qi < 4; qi++) {
      float f = fmaf(qf[qi].z, cp.z,
                fmaf(qf[qi].y, cp.y,
                fmaf(qf[qi].x, cp.x, cp.w + qf[qi].w)));
      mn[qi] = fminf(mn[qi], f);
    }
  }
  // ---- block-wide tau: exact 4th-smallest lane-min over 256 lanes ----
  #pragma unroll
  for (int qi = 0; qi < 4; qi++) {
    float a0, a1, a2, a3;
    wave_top4(mn[qi], a0, a1, a2, a3);
    if (lane == 0) {
      tmpF[qi][wv * 4 + 0] = a0; tmpF[qi][wv * 4 + 1] = a1;
      tmpF[qi][wv * 4 + 2] = a2; tmpF[qi][wv * 4 + 3] = a3;
    }
  }
  __syncthreads();                          // also publishes sCnt = 0
  float g[4];
  #pragma unroll
  for (int qi = 0; qi < 4; qi++) {
    float v = (lane < 16) ? tmpF[qi][lane] : INF;
    float a0, a1, a2, a3;
    wave_top4(v, a0, a1, a2, a3);
    g[qi] = a3 + MARGIN;
  }

  // ---- Pass B: full scan, fast gate -> position-only push (tiny exec-masked bodies) ----
  #pragma unroll 4
  for (int k = 0; k < 32; k++) {
    int j = k * 256 + tid;
    float4 cp = Cb[j];
    float f0 = fmaf(qf[0].z, cp.z, fmaf(qf[0].y, cp.y, fmaf(qf[0].x, cp.x, cp.w + qf[0].w)));
    float f1 = fmaf(qf[1].z, cp.z, fmaf(qf[1].y, cp.y, fmaf(qf[1].x, cp.x, cp.w + qf[1].w)));
    float f2 = fmaf(qf[2].z, cp.z, fmaf(qf[2].y, cp.y, fmaf(qf[2].x, cp.x, cp.w + qf[2].w)));
    float f3 = fmaf(qf[3].z, cp.z, fmaf(qf[3].y, cp.y, fmaf(qf[3].x, cp.x, cp.w + qf[3].w)));
    if (f0 <= g[0]) { int s = atomicAdd(&sCnt[0], 1); if (s < CAP) sPos[0][s] = j; }
    if (f1 <= g[1]) { int s = atomicAdd(&sCnt[1], 1); if (s < CAP) sPos[1][s] = j; }
    if (f2 <= g[2]) { int s = atomicAdd(&sCnt[2], 1); if (s < CAP) sPos[2][s] = j; }
    if (f3 <= g[3]) { int s = atomicAdd(&sCnt[3], 1); if (s < CAP) sPos[3][s] = j; }
  }
  __syncthreads();

  // ---- final: exact keys for survivors, u64 butterfly per (query, mode); 8 pairs / 4 waves ----
  const ull KE = 0x7F800000FFFFFFFFull;
  #pragma unroll
  for (int jj = 0; jj < 2; jj++) {
    int pidx = wv * 2 + jj;
    int qloc = pidx >> 1, mode = pidx & 1;
    int cnt = sCnt[qloc]; cnt = cnt > CAP ? CAP : cnt;
    float qx = -0.5f * qf[qloc].x, qy = -0.5f * qf[qloc].y, qz = -0.5f * qf[qloc].z;
    float qw = qf[qloc].w;
    ull k0 = KE, k1 = KE;
    if (lane < cnt) {
      int pos = sPos[qloc][lane];
      if (mode == 0 || pos < cS) {
        float4 cp = Cb[pos];
        float fe = fmaxf(d2exact_rn(qx, qy, qz, qw, cp.x, cp.y, cp.z, cp.w), 1e-12f);
        unsigned idx = mode ? (unsigned)pos : (unsigned)im[pos];
        k0 = ((ull)__float_as_uint(fe) << 32) | idx;
      }
    }
    if (lane + 64 < cnt) {
      int pos = sPos[qloc][lane + 64];
      if (mode == 0 || pos < cS) {
        float4 cp = Cb[pos];
        float fe = fmaxf(d2exact_rn(qx, qy, qz, qw, cp.x, cp.y, cp.z, cp.w), 1e-12f);
        unsigned idx = mode ? (unsigned)pos : (unsigned)im[pos];
        k1 = ((ull)__float_as_uint(fe) << 32) | idx;
      }
    }
    if (k1 < k0) { ull t = k0; k0 = k1; k1 = t; }
    ull k2 = KE, k3 = KE;
    #pragma unroll
    for (int off = 1; off < 64; off <<= 1) {
      ull b0 = __shfl_xor(k0, off, 64), b1 = __shfl_xor(k1, off, 64);
      ull b2 = __shfl_xor(k2, off, 64), b3 = __shfl_xor(k3, off, 64);
      ull m0 = k0 < b3 ? k0 : b3;
      ull m1 = k1 < b2 ? k1 : b2;
      ull m2 = k2 < b1 ? k2 : b1;
      ull m3 = k3 < b0 ? k3 : b0;
      ce64(m0, m2); ce64(m1, m3); ce64(m0, m1); ce64(m2, m3);
      k0 = m0; k1 = m1; k2 = m2; k3 = m3;
    }
    if (lane == 0) {
      int wq = qbase + qloc;
      int i0 = (int)(unsigned)k0, i1 = (int)(unsigned)k1;
      int i2 = (int)(unsigned)k2, i3 = (int)(unsigned)k3;
      float e1 = sqrtf(__uint_as_float((unsigned)(k1 >> 32)));
      float e2 = sqrtf(__uint_as_float((unsigned)(k2 >> 32)));
      float e3 = sqrtf(__uint_as_float((unsigned)(k3 >> 32)));
      float* tr = trans + wq * cTR + (mode ? 6 : 0);
      tr[0] = e1; tr[1] = e2; tr[2] = e3;
      // anchors in ORIGINAL id space (mode1 keys hold SP idx -> map via im; pos<cS so im ok)
      int* ao = (mode ? AA : AB) + wq * 4;
      if (mode) { i0 = im[i0]; i1 = im[i1]; i2 = im[i2]; i3 = im[i3]; }
      ao[0] = i0; ao[1] = i1; ao[2] = i2; ao[3] = i3;
    }
  }
}

// ---- K3: anchor-anchor dists (intra ch3-5/9-11 + inter ch12-27) + 3-layer MLP ----
// 2048 single-wave blocks, 4 rows/wave, lane = channel (round-9/12 structure, unchanged).
__global__ __launch_bounds__(64) void mlp_kernel(
    const float* __restrict__ TR, const float4* __restrict__ P,
    const int* __restrict__ AB, const int* __restrict__ AA,
    const float* __restrict__ feat, const int* __restrict__ smp,
    const float* __restrict__ w1, const float* __restrict__ b1,
    const float* __restrict__ g1, const float* __restrict__ be1,
    const float* __restrict__ w2, const float* __restrict__ b2,
    const float* __restrict__ g2, const float* __restrict__ be2,
    const float* __restrict__ w3, const float* __restrict__ b3,
    const float* __restrict__ g3, const float* __restrict__ be3,
    float* __restrict__ out) {
  __shared__ alignas(16) float tinT[28 * 4];
  __shared__ alignas(16) float act1T[64 * 4];
  __shared__ alignas(16) float act2T[128 * 4];   // ch 0..63 = feat, 64..127 = L2 out

  const int lane = threadIdx.x;
  const int r0 = blockIdx.x * 4;
  const int b = r0 >> 12;
  const float inv = 1.0f / sqrtf(1.0f + 1e-5f);

  float pb1 = b1[lane], pg1 = g1[lane] * inv, pe1 = be1[lane];
  float pb2 = b2[lane], pg2 = g2[lane] * inv, pe2 = be2[lane];
  float pb3a = b3[lane],      pg3a = g3[lane] * inv,      pe3a = be3[lane];
  float pb3b = b3[lane + 64], pg3b = g3[lane + 64] * inv, pe3b = be3[lane + 64];

  // stage feat -> act2T ch 0..63
  {
    const float* fb = feat + (size_t)b * cN * 64;
    float4 v;
    v.x = fb[smp[r0 + 0] * 64 + lane];
    v.y = fb[smp[r0 + 1] * 64 + lane];
    v.z = fb[smp[r0 + 2] * 64 + lane];
    v.w = fb[smp[r0 + 3] * 64 + lane];
    *(float4*)&act2T[lane * 4] = v;
  }
  // stage tinT (28ch x 4r = 112 items):
  //  ch 0..2 = TR[0..2], ch 3..5 = d(AB pairs (1,2),(1,3),(2,3)), ch 6..8 = TR[6..8],
  //  ch 9..11 = d(AA pairs), ch 12..27 = d(AB[a], AA[bb])
  {
    const float4* Pb = P + b * cN;
    #pragma unroll
    for (int t = 0; t < 2; t++) {
      int idx = t * 64 + lane;
      if (idx < 112) {
        int r = idx & 3, ch = idx >> 2;
        float v;
        if (ch < 3) {
          v = TR[(r0 + r) * cTR + ch];
        } else if (ch < 6) {
          int pi = (ch == 3) ? 1 : 1 + (ch - 4), pj = (ch == 3) ? 2 : 3;
          if (ch == 5) { pi = 2; pj = 3; }
          v = dist_rn4(Pb[AB[(r0 + r) * 4 + pi]], Pb[AB[(r0 + r) * 4 + pj]]);
        } else if (ch < 9) {
          v = TR[(r0 + r) * cTR + ch];
        } else if (ch < 12) {
          int cc = ch - 9;
          int pi = (cc == 0) ? 1 : ((cc == 1) ? 1 : 2);
          int pj = (cc == 0) ? 2 : 3;
          v = dist_rn4(Pb[AA[(r0 + r) * 4 + pi]], Pb[AA[(r0 + r) * 4 + pj]]);
        } else {
          int cc = ch - 12;
          int gi = AB[(r0 + r) * 4 + (cc >> 2)];
          int gj = AA[(r0 + r) * 4 + (cc & 3)];
          v = dist_rn4(Pb[gi], Pb[gj]);
        }
        tinT[ch * 4 + r] = v;
      }
    }
  }
  __syncthreads();

  // L1: 28 -> 64
  {
    float4 acc = make_float4(pb1, pb1, pb1, pb1);
    for (int k = 0; k < 28; k++) {
      float w = w1[k * 64 + lane];
      float4 a = *(const float4*)&tinT[k * 4];
      acc.x = fmaf(a.x, w, acc.x); acc.y = fmaf(a.y, w, acc.y);
      acc.z = fmaf(a.z, w, acc.z); acc.w = fmaf(a.w, w, acc.w);
    }
    float4 o;
    o.x = fmaf(acc.x, pg1, pe1); o.y = fmaf(acc.y, pg1, pe1);
    o.z = fmaf(acc.z, pg1, pe1); o.w = fmaf(acc.w, pg1, pe1);
    o.x = o.x >= 0.0f ? o.x : 0.2f * o.x; o.y = o.y >= 0.0f ? o.y : 0.2f * o.y;
    o.z = o.z >= 0.0f ? o.z : 0.2f * o.z; o.w = o.w >= 0.0f ? o.w : 0.2f * o.w;
    __syncthreads();
    *(float4*)&act1T[lane * 4] = o;
  }
  __syncthreads();
  // L2: 64 -> 64
  {
    float4 acc = make_float4(pb2, pb2, pb2, pb2);
    for (int k = 0; k < 64; k++) {
      float w = w2[k * 64 + lane];
      float4 a = *(const float4*)&act1T[k * 4];
      acc.x = fmaf(a.x, w, acc.x); acc.y = fmaf(a.y, w, acc.y);
      acc.z = fmaf(a.z, w, acc.z); acc.w = fmaf(a.w, w, acc.w);
    }
    float4 o;
    o.x = fmaf(acc.x, pg2, pe2); o.y = fmaf(acc.y, pg2, pe2);
    o.z = fmaf(acc.z, pg2, pe2); o.w = fmaf(acc.w, pg2, pe2);
    o.x = o.x >= 0.0f ? o.x : 0.2f * o.x; o.y = o.y >= 0.0f ? o.y : 0.2f * o.y;
    o.z = o.z >= 0.0f ? o.z : 0.2f * o.z; o.w = o.w >= 0.0f ? o.w : 0.2f * o.w;
    *(float4*)&act2T[(64 + lane) * 4] = o;
  }
  __syncthreads();
  // L3: 128 -> 128 (lane covers ch and ch+64)
  {
    float4 aA = make_float4(pb3a, pb3a, pb3a, pb3a);
    float4 aB = make_float4(pb3b, pb3b, pb3b, pb3b);
    for (int k = 0; k < 128; k++) {
      float wA = w3[k * 128 + lane];
      float wB = w3[k * 128 + 64 + lane];
      float4 a = *(const float4*)&act2T[k * 4];
      aA.x = fmaf(a.x, wA, aA.x); aA.y = fmaf(a.y, wA, aA.y);
      aA.z = fmaf(a.z, wA, aA.z); aA.w = fmaf(a.w, wA, aA.w);
      aB.x = fmaf(a.x, wB, aB.x); aB.y = fmaf(a.y, wB, aB.y);
      aB.z = fmaf(a.z, wB, aB.z); aB.w = fmaf(a.w, wB, aB.w);
    }
    float rA[4] = {aA.x, aA.y, aA.z, aA.w};
    float rB[4] = {aB.x, aB.y, aB.z, aB.w};
    #pragma unroll
    for (int r = 0; r < 4; r++) {
      float xA = fmaf(rA[r], pg3a, pe3a);
      float xB = fmaf(rB[r], pg3b, pe3b);
      xA = xA >= 0.0f ? xA : 0.2f * xA;
      xB = xB >= 0.0f ? xB : 0.2f * xB;
      out[(r0 + r) * 128 + lane] = xA;
      out[(r0 + r) * 128 + 64 + lane] = xB;
    }
  }
}

extern "C" void kernel_launch(void* const* d_in, const int* in_sizes, int n_in,
                              void* d_out, int out_size, void* d_ws, size_t ws_size,
                              hipStream_t stream) {
  const float* xyz  = (const float*)d_in[0];
  const float* feat = (const float*)d_in[1];
  const int*   smp  = (const int*)d_in[2];
  const float* w1   = (const float*)d_in[3];
  const float* b1   = (const float*)d_in[4];
  const float* g1   = (const float*)d_in[5];
  const float* be1  = (const float*)d_in[6];
  const float* w2   = (const float*)d_in[7];
  const float* b2   = (const float*)d_in[8];
  const float* g2   = (const float*)d_in[9];
  const float* be2  = (const float*)d_in[10];
  const float* w3   = (const float*)d_in[11];
  const float* b3   = (const float*)d_in[12];
  const float* g3   = (const float*)d_in[13];
  const float* be3  = (const float*)d_in[14];
  float* out = (float*)d_out;

  char* ws = (char*)d_ws;
  float4* P      = (float4*)(ws);                 // 262144 B
  float4* P2     = (float4*)(ws + 262144);        // 262144 B
  int*    idxMap = (int*)(ws + 524288);           // 65536 B
  float*  TR     = (float*)(ws + 589824);         // B*S*12*4 = 393216 B
  int*    AB     = (int*)(ws + 983040);           // 131072 B
  int*    AA     = (int*)(ws + 1114112);          // 131072 B

  pack_kernel<<<48, 512, 0, stream>>>(xyz, smp, P, P2, idxMap, out);
  knn_kernel<<<2048, 256, 0, stream>>>(P2, idxMap, TR, AB, AA);
  mlp_kernel<<<2048, 64, 0, stream>>>(TR, P, AB, AA, feat, smp,
                                      w1, b1, g1, be1, w2, b2, g2, be2,
                                      w3, b3, g3, be3, out + cB * cS * 3);
}

// Round 14
// 156.643 us; speedup vs baseline: 1.0364x; 1.0364x over previous
//
#include <hip/hip_runtime.h>
#include <math.h>

// Problem constants (match reference)
constexpr int cB = 2, cN = 8192, cS = 4096;
constexpr int cTR = 12;    // stored trans channels (0-5 before, 6-11 after)
constexpr int CAP = 96;    // survivor slots per query (one buffer; mode-1 = subset pos<cS)

typedef unsigned long long ull;

// ---- exact distance: EXACTLY mirrors reference arithmetic ----
// ref: sq = (x*x + y*y) + z*z ; d2 = (sq_i + sq_j) - 2*dot ; d = sqrt(max(d2,1e-12))
__device__ __forceinline__ float d2exact_rn(float qx, float qy, float qz, float qw,
                                            float cx, float cy, float cz, float cw) {
  float dot = __fadd_rn(__fadd_rn(__fmul_rn(qx, cx), __fmul_rn(qy, cy)), __fmul_rn(qz, cz));
  return __fsub_rn(__fadd_rn(qw, cw), __fmul_rn(2.0f, dot));
}
__device__ __forceinline__ float dist_rn4(float4 a, float4 b) {
  return sqrtf(fmaxf(d2exact_rn(a.x, a.y, a.z, a.w, b.x, b.y, b.z, b.w), 1e-12f));
}
__device__ __forceinline__ void ce64(ull& a, ull& b) {
  ull lo = a < b ? a : b;
  ull hi = a < b ? b : a;
  a = lo; b = hi;
}
// wave-wide sorted top-4 of per-lane value v (all lanes end with identical a0..a3)
__device__ __forceinline__ void wave_top4(float v, float& o0, float& o1, float& o2, float& o3) {
  const float INF = __uint_as_float(0x7f800000u);
  float a0 = v, a1 = INF, a2 = INF, a3 = INF;
  #pragma unroll
  for (int off = 1; off < 64; off <<= 1) {
    float s0 = __shfl_xor(a0, off, 64), s1 = __shfl_xor(a1, off, 64);
    float s2 = __shfl_xor(a2, off, 64), s3 = __shfl_xor(a3, off, 64);
    float n0 = fminf(a0, s3), n1 = fminf(a1, s2), n2 = fminf(a2, s1), n3 = fminf(a3, s0);
    float t;
    t = fminf(n0, n2); n2 = fmaxf(n0, n2); n0 = t;
    t = fminf(n1, n3); n3 = fmaxf(n1, n3); n1 = t;
    t = fminf(n0, n1); n1 = fmaxf(n0, n1); n0 = t;
    t = fminf(n2, n3); n3 = fmaxf(n2, n3); n2 = t;
    a0 = n0; a1 = n1; a2 = n2; a3 = n3;
  }
  o0 = a0; o1 = a1; o2 = a2; o3 = a3;
}

// ---- K1: pack. P = orig order (clean sq); P2 = sampled-first permuted; idxMap -> orig ----
// smp sorted per batch: sampled rank lo via binary search; unsampled pos = cS + n - lo.
__global__ __launch_bounds__(512) void pack_kernel(const float* __restrict__ xyz,
                                                   const int* __restrict__ smp,
                                                   float4* __restrict__ P,
                                                   float4* __restrict__ P2,
                                                   int* __restrict__ idxMap,
                                                   float* __restrict__ oxyz) {
  int t = blockIdx.x * 512 + threadIdx.x;
  if (t < cB * cN) {
    int b = t >> 13, n = t & (cN - 1);
    const float* p = xyz + t * 3;
    float x = p[0], y = p[1], z = p[2];
    float sq = __fadd_rn(__fadd_rn(__fmul_rn(x, x), __fmul_rn(y, y)), __fmul_rn(z, z));
    const int* sb = smp + b * cS;
    int lo = 0, hi = cS;
    while (lo < hi) { int mid = (lo + hi) >> 1; if (sb[mid] < n) lo = mid + 1; else hi = mid; }
    bool flg = (lo < cS) && (sb[lo] == n);
    P[t] = make_float4(x, y, z, sq);
    int pos = flg ? lo : (cS + n - lo);
    int gp = b * cN + pos;
    P2[gp] = make_float4(x, y, z, sq);
    idxMap[gp] = n;
  } else if (t < cB * cN + cB * cS) {
    int j = t - cB * cN;
    int b = j >> 12;
    const float* p = xyz + (b * cN + smp[j]) * 3;
    oxyz[j * 3 + 0] = p[0]; oxyz[j * 3 + 1] = p[1]; oxyz[j * 3 + 2] = p[2];
  }
}

// ---- K2: 4-NN both modes, register-streamed candidates (round-12 structure) ----
// 2048 blocks x 256 thr; block owns 4 queries. Pass A: sampled region, per-lane fast minima;
// block-wide tau = exact 4th-smallest of 256 lane-minima (+MARGIN 2e-3 >> fast/exact gap).
// Pass B: round-12 outer hit-guard (s_cbranch_execz skips whole body when no lane hits);
// interior = position-only push (atomicAdd + store). Final: survivors get exact
// reference-rounded d2 + u64 (d2bits, idx) keys (mode0: orig id; mode1: SP idx = pos) ->
// butterfly select == reference top_k bit-identically.
__global__ __launch_bounds__(256, 4) void knn_kernel(const float4* __restrict__ P2,
                                                     const int* __restrict__ idxMap,
                                                     float* __restrict__ trans,
                                                     int* __restrict__ AB,
                                                     int* __restrict__ AA) {
  __shared__ int sPos[4][CAP];
  __shared__ int sCnt[4];
  __shared__ float tmpF[4][16];

  const int tid = threadIdx.x, wv = tid >> 6, lane = tid & 63;
  const int qbase = blockIdx.x * 4;        // 4 | 4096 -> same batch
  const int b = qbase >> 12;
  const int s0 = qbase & (cS - 1);
  const float4* Cb = P2 + b * cN;
  const int* im = idxMap + b * cN;
  const float INF = __uint_as_float(0x7f800000u);
  const float MARGIN = 2e-3f;

  float4 qf[4];   // fast coeffs (-2x,-2y,-2z,sq); exact coords: x = -0.5*qf.x
  #pragma unroll
  for (int qi = 0; qi < 4; qi++) {
    float4 q = Cb[s0 + qi];                // sampled-first: SP idx == P2 position
    qf[qi] = make_float4(-2.0f * q.x, -2.0f * q.y, -2.0f * q.z, q.w);
  }
  if (tid < 4) sCnt[tid] = 0;

  // ---- Pass A: sampled region (positions [0, cS)), per-lane fast minima ----
  float mn[4] = {INF, INF, INF, INF};
  #pragma unroll 4
  for (int k = 0; k < 16; k++) {
    float4 cp = Cb[k * 256 + tid];
    #pragma unroll
    for (int qi = 0; qi < 4; qi++) {
      float f = fmaf(qf[qi].z, cp.z,
                fmaf(qf[qi].y, cp.y,
                fmaf(qf[qi].x, cp.x, cp.w + qf[qi].w)));
      mn[qi] = fminf(mn[qi], f);
    }
  }
  // ---- block-wide tau: exact 4th-smallest lane-min over 256 lanes ----
  #pragma unroll
  for (int qi = 0; qi < 4; qi++) {
    float a0, a1, a2, a3;
    wave_top4(mn[qi], a0, a1, a2, a3);
    if (lane == 0) {
      tmpF[qi][wv * 4 + 0] = a0; tmpF[qi][wv * 4 + 1] = a1;
      tmpF[qi][wv * 4 + 2] = a2; tmpF[qi][wv * 4 + 3] = a3;
    }
  }
  __syncthreads();                          // also publishes sCnt = 0
  float g[4];
  #pragma unroll
  for (int qi = 0; qi < 4; qi++) {
    float v = (lane < 16) ? tmpF[qi][lane] : INF;
    float a0, a1, a2, a3;
    wave_top4(v, a0, a1, a2, a3);
    g[qi] = a3 + MARGIN;
  }

  // ---- Pass B: full scan, fast gate; outer hit-guard + tiny position-push interior ----
  #pragma unroll 2
  for (int k = 0; k < 32; k++) {
    int j = k * 256 + tid;
    float4 cp = Cb[j];
    float f0 = fmaf(qf[0].z, cp.z, fmaf(qf[0].y, cp.y, fmaf(qf[0].x, cp.x, cp.w + qf[0].w)));
    float f1 = fmaf(qf[1].z, cp.z, fmaf(qf[1].y, cp.y, fmaf(qf[1].x, cp.x, cp.w + qf[1].w)));
    float f2 = fmaf(qf[2].z, cp.z, fmaf(qf[2].y, cp.y, fmaf(qf[2].x, cp.x, cp.w + qf[2].w)));
    float f3 = fmaf(qf[3].z, cp.z, fmaf(qf[3].y, cp.y, fmaf(qf[3].x, cp.x, cp.w + qf[3].w)));
    bool hit = (f0 <= g[0]) | (f1 <= g[1]) | (f2 <= g[2]) | (f3 <= g[3]);
    if (hit) {                             // rare: skipped wholesale when no lane hits
      float fv[4] = {f0, f1, f2, f3};
      #pragma unroll
      for (int qi = 0; qi < 4; qi++) {
        if (fv[qi] <= g[qi]) {
          int s = atomicAdd(&sCnt[qi], 1);
          if (s < CAP) sPos[qi][s] = j;
        }
      }
    }
  }
  __syncthreads();

  // ---- final: exact keys for survivors, u64 butterfly per (query, mode); 8 pairs / 4 waves ----
  const ull KE = 0x7F800000FFFFFFFFull;
  #pragma unroll
  for (int jj = 0; jj < 2; jj++) {
    int pidx = wv * 2 + jj;
    int qloc = pidx >> 1, mode = pidx & 1;
    int cnt = sCnt[qloc]; cnt = cnt > CAP ? CAP : cnt;
    float qx = -0.5f * qf[qloc].x, qy = -0.5f * qf[qloc].y, qz = -0.5f * qf[qloc].z;
    float qw = qf[qloc].w;
    ull k0 = KE, k1 = KE;
    if (lane < cnt) {
      int pos = sPos[qloc][lane];
      if (mode == 0 || pos < cS) {
        float4 cp = Cb[pos];
        float fe = fmaxf(d2exact_rn(qx, qy, qz, qw, cp.x, cp.y, cp.z, cp.w), 1e-12f);
        unsigned idx = mode ? (unsigned)pos : (unsigned)im[pos];
        k0 = ((ull)__float_as_uint(fe) << 32) | idx;
      }
    }
    if (lane + 64 < cnt) {
      int pos = sPos[qloc][lane + 64];
      if (mode == 0 || pos < cS) {
        float4 cp = Cb[pos];
        float fe = fmaxf(d2exact_rn(qx, qy, qz, qw, cp.x, cp.y, cp.z, cp.w), 1e-12f);
        unsigned idx = mode ? (unsigned)pos : (unsigned)im[pos];
        k1 = ((ull)__float_as_uint(fe) << 32) | idx;
      }
    }
    if (k1 < k0) { ull t = k0; k0 = k1; k1 = t; }
    ull k2 = KE, k3 = KE;
    #pragma unroll
    for (int off = 1; off < 64; off <<= 1) {
      ull b0 = __shfl_xor(k0, off, 64), b1 = __shfl_xor(k1, off, 64);
      ull b2 = __shfl_xor(k2, off, 64), b3 = __shfl_xor(k3, off, 64);
      ull m0 = k0 < b3 ? k0 : b3;
      ull m1 = k1 < b2 ? k1 : b2;
      ull m2 = k2 < b1 ? k2 : b1;
      ull m3 = k3 < b0 ? k3 : b0;
      ce64(m0, m2); ce64(m1, m3); ce64(m0, m1); ce64(m2, m3);
      k0 = m0; k1 = m1; k2 = m2; k3 = m3;
    }
    if (lane == 0) {
      int wq = qbase + qloc;
      int i0 = (int)(unsigned)k0, i1 = (int)(unsigned)k1;
      int i2 = (int)(unsigned)k2, i3 = (int)(unsigned)k3;
      float e1 = sqrtf(__uint_as_float((unsigned)(k1 >> 32)));
      float e2 = sqrtf(__uint_as_float((unsigned)(k2 >> 32)));
      float e3 = sqrtf(__uint_as_float((unsigned)(k3 >> 32)));
      float* tr = trans + wq * cTR + (mode ? 6 : 0);
      tr[0] = e1; tr[1] = e2; tr[2] = e3;
      int* ao = (mode ? AA : AB) + wq * 4;
      if (mode) { i0 = im[i0]; i1 = im[i1]; i2 = im[i2]; i3 = im[i3]; }
      ao[0] = i0; ao[1] = i1; ao[2] = i2; ao[3] = i3;
    }
  }
}

// ---- K3: anchor-anchor dists (intra ch3-5/9-11 + inter ch12-27) + 3-layer MLP ----
// 2048 single-wave blocks, 4 rows/wave, lane = channel (round-12 structure, unchanged).
__global__ __launch_bounds__(64) void mlp_kernel(
    const float* __restrict__ TR, const float4* __restrict__ P,
    const int* __restrict__ AB, const int* __restrict__ AA,
    const float* __restrict__ feat, const int* __restrict__ smp,
    const float* __restrict__ w1, const float* __restrict__ b1,
    const float* __restrict__ g1, const float* __restrict__ be1,
    const float* __restrict__ w2, const float* __restrict__ b2,
    const float* __restrict__ g2, const float* __restrict__ be2,
    const float* __restrict__ w3, const float* __restrict__ b3,
    const float* __restrict__ g3, const float* __restrict__ be3,
    float* __restrict__ out) {
  __shared__ alignas(16) float tinT[28 * 4];
  __shared__ alignas(16) float act1T[64 * 4];
  __shared__ alignas(16) float act2T[128 * 4];   // ch 0..63 = feat, 64..127 = L2 out

  const int lane = threadIdx.x;
  const int r0 = blockIdx.x * 4;
  const int b = r0 >> 12;
  const float inv = 1.0f / sqrtf(1.0f + 1e-5f);

  float pb1 = b1[lane], pg1 = g1[lane] * inv, pe1 = be1[lane];
  float pb2 = b2[lane], pg2 = g2[lane] * inv, pe2 = be2[lane];
  float pb3a = b3[lane],      pg3a = g3[lane] * inv,      pe3a = be3[lane];
  float pb3b = b3[lane + 64], pg3b = g3[lane + 64] * inv, pe3b = be3[lane + 64];

  // stage feat -> act2T ch 0..63
  {
    const float* fb = feat + (size_t)b * cN * 64;
    float4 v;
    v.x = fb[smp[r0 + 0] * 64 + lane];
    v.y = fb[smp[r0 + 1] * 64 + lane];
    v.z = fb[smp[r0 + 2] * 64 + lane];
    v.w = fb[smp[r0 + 3] * 64 + lane];
    *(float4*)&act2T[lane * 4] = v;
  }
  // stage tinT (28ch x 4r = 112 items):
  //  ch 0..2 = TR[0..2], ch 3..5 = d(AB pairs (1,2),(1,3),(2,3)), ch 6..8 = TR[6..8],
  //  ch 9..11 = d(AA pairs), ch 12..27 = d(AB[a], AA[bb])
  {
    const float4* Pb = P + b * cN;
    #pragma unroll
    for (int t = 0; t < 2; t++) {
      int idx = t * 64 + lane;
      if (idx < 112) {
        int r = idx & 3, ch = idx >> 2;
        float v;
        if (ch < 3) {
          v = TR[(r0 + r) * cTR + ch];
        } else if (ch < 6) {
          int pi = (ch == 3) ? 1 : 1 + (ch - 4), pj = (ch == 3) ? 2 : 3;
          if (ch == 5) { pi = 2; pj = 3; }
          v = dist_rn4(Pb[AB[(r0 + r) * 4 + pi]], Pb[AB[(r0 + r) * 4 + pj]]);
        } else if (ch < 9) {
          v = TR[(r0 + r) * cTR + ch];
        } else if (ch < 12) {
          int cc = ch - 9;
          int pi = (cc == 0) ? 1 : ((cc == 1) ? 1 : 2);
          int pj = (cc == 0) ? 2 : 3;
          v = dist_rn4(Pb[AA[(r0 + r) * 4 + pi]], Pb[AA[(r0 + r) * 4 + pj]]);
        } else {
          int cc = ch - 12;
          int gi = AB[(r0 + r) * 4 + (cc >> 2)];
          int gj = AA[(r0 + r) * 4 + (cc & 3)];
          v = dist_rn4(Pb[gi], Pb[gj]);
        }
        tinT[ch * 4 + r] = v;
      }
    }
  }
  __syncthreads();

  // L1: 28 -> 64
  {
    float4 acc = make_float4(pb1, pb1, pb1, pb1);
    for (int k = 0; k < 28; k++) {
      float w = w1[k * 64 + lane];
      float4 a = *(const float4*)&tinT[k * 4];
      acc.x = fmaf(a.x, w, acc.x); acc.y = fmaf(a.y, w, acc.y);
      acc.z = fmaf(a.z, w, acc.z); acc.w = fmaf(a.w, w, acc.w);
    }
    float4 o;
    o.x = fmaf(acc.x, pg1, pe1); o.y = fmaf(acc.y, pg1, pe1);
    o.z = fmaf(acc.z, pg1, pe1); o.w = fmaf(acc.w, pg1, pe1);
    o.x = o.x >= 0.0f ? o.x : 0.2f * o.x; o.y = o.y >= 0.0f ? o.y : 0.2f * o.y;
    o.z = o.z >= 0.0f ? o.z : 0.2f * o.z; o.w = o.w >= 0.0f ? o.w : 0.2f * o.w;
    __syncthreads();
    *(float4*)&act1T[lane * 4] = o;
  }
  __syncthreads();
  // L2: 64 -> 64
  {
    float4 acc = make_float4(pb2, pb2, pb2, pb2);
    for (int k = 0; k < 64; k++) {
      float w = w2[k * 64 + lane];
      float4 a = *(const float4*)&act1T[k * 4];
      acc.x = fmaf(a.x, w, acc.x); acc.y = fmaf(a.y, w, acc.y);
      acc.z = fmaf(a.z, w, acc.z); acc.w = fmaf(a.w, w, acc.w);
    }
    float4 o;
    o.x = fmaf(acc.x, pg2, pe2); o.y = fmaf(acc.y, pg2, pe2);
    o.z = fmaf(acc.z, pg2, pe2); o.w = fmaf(acc.w, pg2, pe2);
    o.x = o.x >= 0.0f ? o.x : 0.2f * o.x; o.y = o.y >= 0.0f ? o.y : 0.2f * o.y;
    o.z = o.z >= 0.0f ? o.z : 0.2f * o.z; o.w = o.w >= 0.0f ? o.w : 0.2f * o.w;
    *(float4*)&act2T[(64 + lane) * 4] = o;
  }
  __syncthreads();
  // L3: 128 -> 128 (lane covers ch and ch+64)
  {
    float4 aA = make_float4(pb3a, pb3a, pb3a, pb3a);
    float4 aB = make_float4(pb3b, pb3b, pb3b, pb3b);
    for (int k = 0; k < 128; k++) {
      float wA = w3[k * 128 + lane];
      float wB = w3[k * 128 + 64 + lane];
      float4 a = *(const float4*)&act2T[k * 4];
      aA.x = fmaf(a.x, wA, aA.x); aA.y = fmaf(a.y, wA, aA.y);
      aA.z = fmaf(a.z, wA, aA.z); aA.w = fmaf(a.w, wA, aA.w);
      aB.x = fmaf(a.x, wB, aB.x); aB.y = fmaf(a.y, wB, aB.y);
      aB.z = fmaf(a.z, wB, aB.z); aB.w = fmaf(a.w, wB, aB.w);
    }
    float rA[4] = {aA.x, aA.y, aA.z, aA.w};
    float rB[4] = {aB.x, aB.y, aB.z, aB.w};
    #pragma unroll
    for (int r = 0; r < 4; r++) {
      float xA = fmaf(rA[r], pg3a, pe3a);
      float xB = fmaf(rB[r], pg3b, pe3b);
      xA = xA >= 0.0f ? xA : 0.2f * xA;
      xB = xB >= 0.0f ? xB : 0.2f * xB;
      out[(r0 + r) * 128 + lane] = xA;
      out[(r0 + r) * 128 + 64 + lane] = xB;
    }
  }
}

extern "C" void kernel_launch(void* const* d_in, const int* in_sizes, int n_in,
                              void* d_out, int out_size, void* d_ws, size_t ws_size,
                              hipStream_t stream) {
  const float* xyz  = (const float*)d_in[0];
  const float* feat = (const float*)d_in[1];
  const int*   smp  = (const int*)d_in[2];
  const float* w1   = (const float*)d_in[3];
  const float* b1   = (const float*)d_in[4];
  const float* g1   = (const float*)d_in[5];
  const float* be1  = (const float*)d_in[6];
  const float* w2   = (const float*)d_in[7];
  const float* b2   = (const float*)d_in[8];
  const float* g2   = (const float*)d_in[9];
  const float* be2  = (const float*)d_in[10];
  const float* w3   = (const float*)d_in[11];
  const float* b3   = (const float*)d_in[12];
  const float* g3   = (const float*)d_in[13];
  const float* be3  = (const float*)d_in[14];
  float* out = (float*)d_out;

  char* ws = (char*)d_ws;
  float4* P      = (float4*)(ws);                 // 262144 B
  float4* P2     = (float4*)(ws + 262144);        // 262144 B
  int*    idxMap = (int*)(ws + 524288);           // 65536 B
  float*  TR     = (float*)(ws + 589824);         // B*S*12*4 = 393216 B
  int*    AB     = (int*)(ws + 983040);           // 131072 B
  int*    AA     = (int*)(ws + 1114112);          // 131072 B

  pack_kernel<<<48, 512, 0, stream>>>(xyz, smp, P, P2, idxMap, out);
  knn_kernel<<<2048, 256, 0, stream>>>(P2, idxMap, TR, AB, AA);
  mlp_kernel<<<2048, 64, 0, stream>>>(TR, P, AB, AA, feat, smp,
                                      w1, b1, g1, be1, w2, b2, g2, be2,
                                      w3, b3, g3, be3, out + cB * cS * 3);
}

// Round 15
// 143.953 us; speedup vs baseline: 1.1278x; 1.0881x over previous
//
#include <hip/hip_runtime.h>
#include <math.h>

// Problem constants (match reference)
constexpr int cB = 2, cN = 8192, cS = 4096;
constexpr int cTR = 12;    // stored trans channels (0-5 before, 6-11 after)
constexpr int CAP = 96;    // survivor slots per query (one buffer; mode-1 = subset pos<cS)

typedef unsigned long long ull;

// ---- exact distance: EXACTLY mirrors reference arithmetic ----
// ref: sq = (x*x + y*y) + z*z ; d2 = (sq_i + sq_j) - 2*dot ; d = sqrt(max(d2,1e-12))
__device__ __forceinline__ float d2exact_rn(float qx, float qy, float qz, float qw,
                                            float cx, float cy, float cz, float cw) {
  float dot = __fadd_rn(__fadd_rn(__fmul_rn(qx, cx), __fmul_rn(qy, cy)), __fmul_rn(qz, cz));
  return __fsub_rn(__fadd_rn(qw, cw), __fmul_rn(2.0f, dot));
}
__device__ __forceinline__ float dist_rn4(float4 a, float4 b) {
  return sqrtf(fmaxf(d2exact_rn(a.x, a.y, a.z, a.w, b.x, b.y, b.z, b.w), 1e-12f));
}
__device__ __forceinline__ void ce64(ull& a, ull& b) {
  ull lo = a < b ? a : b;
  ull hi = a < b ? b : a;
  a = lo; b = hi;
}
// wave-wide sorted top-4 of per-lane value v (all lanes end with identical a0..a3)
__device__ __forceinline__ void wave_top4(float v, float& o0, float& o1, float& o2, float& o3) {
  const float INF = __uint_as_float(0x7f800000u);
  float a0 = v, a1 = INF, a2 = INF, a3 = INF;
  #pragma unroll
  for (int off = 1; off < 64; off <<= 1) {
    float s0 = __shfl_xor(a0, off, 64), s1 = __shfl_xor(a1, off, 64);
    float s2 = __shfl_xor(a2, off, 64), s3 = __shfl_xor(a3, off, 64);
    float n0 = fminf(a0, s3), n1 = fminf(a1, s2), n2 = fminf(a2, s1), n3 = fminf(a3, s0);
    float t;
    t = fminf(n0, n2); n2 = fmaxf(n0, n2); n0 = t;
    t = fminf(n1, n3); n3 = fmaxf(n1, n3); n1 = t;
    t = fminf(n0, n1); n1 = fmaxf(n0, n1); n0 = t;
    t = fminf(n2, n3); n3 = fmaxf(n2, n3); n2 = t;
    a0 = n0; a1 = n1; a2 = n2; a3 = n3;
  }
  o0 = a0; o1 = a1; o2 = a2; o3 = a3;
}

// ---- K1: pack. P = orig order (clean sq); P2 = sampled-first permuted; idxMap -> orig ----
// smp sorted per batch: sampled rank lo via binary search; unsampled pos = cS + n - lo.
__global__ __launch_bounds__(512) void pack_kernel(const float* __restrict__ xyz,
                                                   const int* __restrict__ smp,
                                                   float4* __restrict__ P,
                                                   float4* __restrict__ P2,
                                                   int* __restrict__ idxMap,
                                                   float* __restrict__ oxyz) {
  int t = blockIdx.x * 512 + threadIdx.x;
  if (t < cB * cN) {
    int b = t >> 13, n = t & (cN - 1);
    const float* p = xyz + t * 3;
    float x = p[0], y = p[1], z = p[2];
    float sq = __fadd_rn(__fadd_rn(__fmul_rn(x, x), __fmul_rn(y, y)), __fmul_rn(z, z));
    const int* sb = smp + b * cS;
    int lo = 0, hi = cS;
    while (lo < hi) { int mid = (lo + hi) >> 1; if (sb[mid] < n) lo = mid + 1; else hi = mid; }
    bool flg = (lo < cS) && (sb[lo] == n);
    P[t] = make_float4(x, y, z, sq);
    int pos = flg ? lo : (cS + n - lo);
    int gp = b * cN + pos;
    P2[gp] = make_float4(x, y, z, sq);
    idxMap[gp] = n;
  } else if (t < cB * cN + cB * cS) {
    int j = t - cB * cN;
    int b = j >> 12;
    const float* p = xyz + (b * cN + smp[j]) * 3;
    oxyz[j * 3 + 0] = p[0]; oxyz[j * 3 + 1] = p[1]; oxyz[j * 3 + 2] = p[2];
  }
}

// ---- K2: 4-NN both modes, register-streamed candidates, ALL per-thread state scalarized ----
// (r13/14 lesson: any local array here gets LDS-promoted by AMDGPUPromoteAlloca when the
// declared LDS is small -> 16 KB per-block LDS, 884k bank conflicts, 46% VALUBusy. No arrays.)
// 2048 blocks x 256 thr; block owns 4 queries. Pass A: sampled region, per-lane fast minima;
// block-wide tau = exact 4th-smallest of 256 lane-minima (+MARGIN 2e-3 >> fast/exact gap).
// Pass B: outer hit-guard + position-only push. Final: survivors get exact reference-rounded
// d2 + u64 (d2bits, idx) keys (mode0: orig id; mode1: SP idx = pos) -> butterfly select
// == reference top_k bit-identically.
__global__ __launch_bounds__(256, 4) void knn_kernel(const float4* __restrict__ P2,
                                                     const int* __restrict__ idxMap,
                                                     float* __restrict__ trans,
                                                     int* __restrict__ AB,
                                                     int* __restrict__ AA) {
  __shared__ int sPos[4][CAP];
  __shared__ int sCnt[4];
  __shared__ float tmpF[4][16];

  const int tid = threadIdx.x, wv = tid >> 6, lane = tid & 63;
  const int qbase = blockIdx.x * 4;        // 4 | 4096 -> same batch
  const int b = qbase >> 12;
  const int s0 = qbase & (cS - 1);
  const float4* Cb = P2 + b * cN;
  const int* im = idxMap + b * cN;
  const float INF = __uint_as_float(0x7f800000u);
  const float MARGIN = 2e-3f;

  // fast coeffs (-2x,-2y,-2z,sq) as named float4 values (never indexed -> registers)
  float4 q0 = Cb[s0 + 0], q1 = Cb[s0 + 1], q2 = Cb[s0 + 2], q3 = Cb[s0 + 3];
  const float4 qf0 = make_float4(-2.0f * q0.x, -2.0f * q0.y, -2.0f * q0.z, q0.w);
  const float4 qf1 = make_float4(-2.0f * q1.x, -2.0f * q1.y, -2.0f * q1.z, q1.w);
  const float4 qf2 = make_float4(-2.0f * q2.x, -2.0f * q2.y, -2.0f * q2.z, q2.w);
  const float4 qf3 = make_float4(-2.0f * q3.x, -2.0f * q3.y, -2.0f * q3.z, q3.w);
  if (tid < 4) sCnt[tid] = 0;

  // ---- Pass A: sampled region (positions [0, cS)), per-lane fast minima ----
  float mn0 = INF, mn1 = INF, mn2 = INF, mn3 = INF;
  #pragma unroll 4
  for (int k = 0; k < 16; k++) {
    float4 cp = Cb[k * 256 + tid];
    mn0 = fminf(mn0, fmaf(qf0.z, cp.z, fmaf(qf0.y, cp.y, fmaf(qf0.x, cp.x, cp.w + qf0.w))));
    mn1 = fminf(mn1, fmaf(qf1.z, cp.z, fmaf(qf1.y, cp.y, fmaf(qf1.x, cp.x, cp.w + qf1.w))));
    mn2 = fminf(mn2, fmaf(qf2.z, cp.z, fmaf(qf2.y, cp.y, fmaf(qf2.x, cp.x, cp.w + qf2.w))));
    mn3 = fminf(mn3, fmaf(qf3.z, cp.z, fmaf(qf3.y, cp.y, fmaf(qf3.x, cp.x, cp.w + qf3.w))));
  }
  // ---- block-wide tau: exact 4th-smallest lane-min over 256 lanes ----
  {
    float a0, a1, a2, a3;
    wave_top4(mn0, a0, a1, a2, a3);
    if (lane == 0) { tmpF[0][wv*4+0]=a0; tmpF[0][wv*4+1]=a1; tmpF[0][wv*4+2]=a2; tmpF[0][wv*4+3]=a3; }
    wave_top4(mn1, a0, a1, a2, a3);
    if (lane == 0) { tmpF[1][wv*4+0]=a0; tmpF[1][wv*4+1]=a1; tmpF[1][wv*4+2]=a2; tmpF[1][wv*4+3]=a3; }
    wave_top4(mn2, a0, a1, a2, a3);
    if (lane == 0) { tmpF[2][wv*4+0]=a0; tmpF[2][wv*4+1]=a1; tmpF[2][wv*4+2]=a2; tmpF[2][wv*4+3]=a3; }
    wave_top4(mn3, a0, a1, a2, a3);
    if (lane == 0) { tmpF[3][wv*4+0]=a0; tmpF[3][wv*4+1]=a1; tmpF[3][wv*4+2]=a2; tmpF[3][wv*4+3]=a3; }
  }
  __syncthreads();                          // also publishes sCnt = 0
  float g0, g1, g2, g3;
  {
    float a0, a1, a2, a3;
    wave_top4((lane < 16) ? tmpF[0][lane] : INF, a0, a1, a2, a3); g0 = a3 + MARGIN;
    wave_top4((lane < 16) ? tmpF[1][lane] : INF, a0, a1, a2, a3); g1 = a3 + MARGIN;
    wave_top4((lane < 16) ? tmpF[2][lane] : INF, a0, a1, a2, a3); g2 = a3 + MARGIN;
    wave_top4((lane < 16) ? tmpF[3][lane] : INF, a0, a1, a2, a3); g3 = a3 + MARGIN;
  }

  // ---- Pass B: full scan, fast gate; outer hit-guard + tiny position-push interior ----
  #pragma unroll 2
  for (int k = 0; k < 32; k++) {
    int j = k * 256 + tid;
    float4 cp = Cb[j];
    float f0 = fmaf(qf0.z, cp.z, fmaf(qf0.y, cp.y, fmaf(qf0.x, cp.x, cp.w + qf0.w)));
    float f1 = fmaf(qf1.z, cp.z, fmaf(qf1.y, cp.y, fmaf(qf1.x, cp.x, cp.w + qf1.w)));
    float f2 = fmaf(qf2.z, cp.z, fmaf(qf2.y, cp.y, fmaf(qf2.x, cp.x, cp.w + qf2.w)));
    float f3 = fmaf(qf3.z, cp.z, fmaf(qf3.y, cp.y, fmaf(qf3.x, cp.x, cp.w + qf3.w)));
    bool hit = (f0 <= g0) | (f1 <= g1) | (f2 <= g2) | (f3 <= g3);
    if (hit) {                             // rare: skipped wholesale when no lane hits
      if (f0 <= g0) { int s = atomicAdd(&sCnt[0], 1); if (s < CAP) sPos[0][s] = j; }
      if (f1 <= g1) { int s = atomicAdd(&sCnt[1], 1); if (s < CAP) sPos[1][s] = j; }
      if (f2 <= g2) { int s = atomicAdd(&sCnt[2], 1); if (s < CAP) sPos[2][s] = j; }
      if (f3 <= g3) { int s = atomicAdd(&sCnt[3], 1); if (s < CAP) sPos[3][s] = j; }
    }
  }
  __syncthreads();

  // ---- final: exact keys for survivors, u64 butterfly per (query, mode); 8 pairs / 4 waves ----
  const ull KE = 0x7F800000FFFFFFFFull;
  const int qloc = wv;                      // wave handles its query's two modes
  const float4 qv = Cb[s0 + qloc];          // exact coords, L2-hot re-read (no dynamic qf[])
  #pragma unroll
  for (int mode = 0; mode < 2; mode++) {
    int cnt = sCnt[qloc]; cnt = cnt > CAP ? CAP : cnt;
    ull k0 = KE, k1 = KE;
    if (lane < cnt) {
      int pos = sPos[qloc][lane];
      if (mode == 0 || pos < cS) {
        float4 cp = Cb[pos];
        float fe = fmaxf(d2exact_rn(qv.x, qv.y, qv.z, qv.w, cp.x, cp.y, cp.z, cp.w), 1e-12f);
        unsigned idx = mode ? (unsigned)pos : (unsigned)im[pos];
        k0 = ((ull)__float_as_uint(fe) << 32) | idx;
      }
    }
    if (lane + 64 < cnt) {
      int pos = sPos[qloc][lane + 64];
      if (mode == 0 || pos < cS) {
        float4 cp = Cb[pos];
        float fe = fmaxf(d2exact_rn(qv.x, qv.y, qv.z, qv.w, cp.x, cp.y, cp.z, cp.w), 1e-12f);
        unsigned idx = mode ? (unsigned)pos : (unsigned)im[pos];
        k1 = ((ull)__float_as_uint(fe) << 32) | idx;
      }
    }
    if (k1 < k0) { ull t = k0; k0 = k1; k1 = t; }
    ull k2 = KE, k3 = KE;
    #pragma unroll
    for (int off = 1; off < 64; off <<= 1) {
      ull b0 = __shfl_xor(k0, off, 64), b1 = __shfl_xor(k1, off, 64);
      ull b2 = __shfl_xor(k2, off, 64), b3 = __shfl_xor(k3, off, 64);
      ull m0 = k0 < b3 ? k0 : b3;
      ull m1 = k1 < b2 ? k1 : b2;
      ull m2 = k2 < b1 ? k2 : b1;
      ull m3 = k3 < b0 ? k3 : b0;
      ce64(m0, m2); ce64(m1, m3); ce64(m0, m1); ce64(m2, m3);
      k0 = m0; k1 = m1; k2 = m2; k3 = m3;
    }
    if (lane == 0) {
      int wq = qbase + qloc;
      int i0 = (int)(unsigned)k0, i1 = (int)(unsigned)k1;
      int i2 = (int)(unsigned)k2, i3 = (int)(unsigned)k3;
      float e1 = sqrtf(__uint_as_float((unsigned)(k1 >> 32)));
      float e2 = sqrtf(__uint_as_float((unsigned)(k2 >> 32)));
      float e3 = sqrtf(__uint_as_float((unsigned)(k3 >> 32)));
      float* tr = trans + wq * cTR + (mode ? 6 : 0);
      tr[0] = e1; tr[1] = e2; tr[2] = e3;
      int* ao = (mode ? AA : AB) + wq * 4;
      if (mode) { i0 = im[i0]; i1 = im[i1]; i2 = im[i2]; i3 = im[i3]; }
      ao[0] = i0; ao[1] = i1; ao[2] = i2; ao[3] = i3;
    }
  }
}

// ---- K3: anchor-anchor dists (intra ch3-5/9-11 + inter ch12-27) + 3-layer MLP ----
// 2048 single-wave blocks, 4 rows/wave, lane = channel (round-12 structure, unchanged).
__global__ __launch_bounds__(64) void mlp_kernel(
    const float* __restrict__ TR, const float4* __restrict__ P,
    const int* __restrict__ AB, const int* __restrict__ AA,
    const float* __restrict__ feat, const int* __restrict__ smp,
    const float* __restrict__ w1, const float* __restrict__ b1,
    const float* __restrict__ g1, const float* __restrict__ be1,
    const float* __restrict__ w2, const float* __restrict__ b2,
    const float* __restrict__ g2, const float* __restrict__ be2,
    const float* __restrict__ w3, const float* __restrict__ b3,
    const float* __restrict__ g3, const float* __restrict__ be3,
    float* __restrict__ out) {
  __shared__ alignas(16) float tinT[28 * 4];
  __shared__ alignas(16) float act1T[64 * 4];
  __shared__ alignas(16) float act2T[128 * 4];   // ch 0..63 = feat, 64..127 = L2 out

  const int lane = threadIdx.x;
  const int r0 = blockIdx.x * 4;
  const int b = r0 >> 12;
  const float inv = 1.0f / sqrtf(1.0f + 1e-5f);

  float pb1 = b1[lane], pg1 = g1[lane] * inv, pe1 = be1[lane];
  float pb2 = b2[lane], pg2 = g2[lane] * inv, pe2 = be2[lane];
  float pb3a = b3[lane],      pg3a = g3[lane] * inv,      pe3a = be3[lane];
  float pb3b = b3[lane + 64], pg3b = g3[lane + 64] * inv, pe3b = be3[lane + 64];

  // stage feat -> act2T ch 0..63
  {
    const float* fb = feat + (size_t)b * cN * 64;
    float4 v;
    v.x = fb[smp[r0 + 0] * 64 + lane];
    v.y = fb[smp[r0 + 1] * 64 + lane];
    v.z = fb[smp[r0 + 2] * 64 + lane];
    v.w = fb[smp[r0 + 3] * 64 + lane];
    *(float4*)&act2T[lane * 4] = v;
  }
  // stage tinT (28ch x 4r = 112 items):
  //  ch 0..2 = TR[0..2], ch 3..5 = d(AB pairs (1,2),(1,3),(2,3)), ch 6..8 = TR[6..8],
  //  ch 9..11 = d(AA pairs), ch 12..27 = d(AB[a], AA[bb])
  {
    const float4* Pb = P + b * cN;
    #pragma unroll
    for (int t = 0; t < 2; t++) {
      int idx = t * 64 + lane;
      if (idx < 112) {
        int r = idx & 3, ch = idx >> 2;
        float v;
        if (ch < 3) {
          v = TR[(r0 + r) * cTR + ch];
        } else if (ch < 6) {
          int pi = (ch == 3) ? 1 : 1 + (ch - 4), pj = (ch == 3) ? 2 : 3;
          if (ch == 5) { pi = 2; pj = 3; }
          v = dist_rn4(Pb[AB[(r0 + r) * 4 + pi]], Pb[AB[(r0 + r) * 4 + pj]]);
        } else if (ch < 9) {
          v = TR[(r0 + r) * cTR + ch];
        } else if (ch < 12) {
          int cc = ch - 9;
          int pi = (cc == 0) ? 1 : ((cc == 1) ? 1 : 2);
          int pj = (cc == 0) ? 2 : 3;
          v = dist_rn4(Pb[AA[(r0 + r) * 4 + pi]], Pb[AA[(r0 + r) * 4 + pj]]);
        } else {
          int cc = ch - 12;
          int gi = AB[(r0 + r) * 4 + (cc >> 2)];
          int gj = AA[(r0 + r) * 4 + (cc & 3)];
          v = dist_rn4(Pb[gi], Pb[gj]);
        }
        tinT[ch * 4 + r] = v;
      }
    }
  }
  __syncthreads();

  // L1: 28 -> 64
  {
    float4 acc = make_float4(pb1, pb1, pb1, pb1);
    for (int k = 0; k < 28; k++) {
      float w = w1[k * 64 + lane];
      float4 a = *(const float4*)&tinT[k * 4];
      acc.x = fmaf(a.x, w, acc.x); acc.y = fmaf(a.y, w, acc.y);
      acc.z = fmaf(a.z, w, acc.z); acc.w = fmaf(a.w, w, acc.w);
    }
    float4 o;
    o.x = fmaf(acc.x, pg1, pe1); o.y = fmaf(acc.y, pg1, pe1);
    o.z = fmaf(acc.z, pg1, pe1); o.w = fmaf(acc.w, pg1, pe1);
    o.x = o.x >= 0.0f ? o.x : 0.2f * o.x; o.y = o.y >= 0.0f ? o.y : 0.2f * o.y;
    o.z = o.z >= 0.0f ? o.z : 0.2f * o.z; o.w = o.w >= 0.0f ? o.w : 0.2f * o.w;
    __syncthreads();
    *(float4*)&act1T[lane * 4] = o;
  }
  __syncthreads();
  // L2: 64 -> 64
  {
    float4 acc = make_float4(pb2, pb2, pb2, pb2);
    for (int k = 0; k < 64; k++) {
      float w = w2[k * 64 + lane];
      float4 a = *(const float4*)&act1T[k * 4];
      acc.x = fmaf(a.x, w, acc.x); acc.y = fmaf(a.y, w, acc.y);
      acc.z = fmaf(a.z, w, acc.z); acc.w = fmaf(a.w, w, acc.w);
    }
    float4 o;
    o.x = fmaf(acc.x, pg2, pe2); o.y = fmaf(acc.y, pg2, pe2);
    o.z = fmaf(acc.z, pg2, pe2); o.w = fmaf(acc.w, pg2, pe2);
    o.x = o.x >= 0.0f ? o.x : 0.2f * o.x; o.y = o.y >= 0.0f ? o.y : 0.2f * o.y;
    o.z = o.z >= 0.0f ? o.z : 0.2f * o.z; o.w = o.w >= 0.0f ? o.w : 0.2f * o.w;
    *(float4*)&act2T[(64 + lane) * 4] = o;
  }
  __syncthreads();
  // L3: 128 -> 128 (lane covers ch and ch+64)
  {
    float4 aA = make_float4(pb3a, pb3a, pb3a, pb3a);
    float4 aB = make_float4(pb3b, pb3b, pb3b, pb3b);
    for (int k = 0; k < 128; k++) {
      float wA = w3[k * 128 + lane];
      float wB = w3[k * 128 + 64 + lane];
      float4 a = *(const float4*)&act2T[k * 4];
      aA.x = fmaf(a.x, wA, aA.x); aA.y = fmaf(a.y, wA, aA.y);
      aA.z = fmaf(a.z, wA, aA.z); aA.w = fmaf(a.w, wA, aA.w);
      aB.x = fmaf(a.x, wB, aB.x); aB.y = fmaf(a.y, wB, aB.y);
      aB.z = fmaf(a.z, wB, aB.z); aB.w = fmaf(a.w, wB, aB.w);
    }
    float rA0 = aA.x, rA1 = aA.y, rA2 = aA.z, rA3 = aA.w;
    float rB0 = aB.x, rB1 = aB.y, rB2 = aB.z, rB3 = aB.w;
    float xA, xB;
    xA = fmaf(rA0, pg3a, pe3a); xB = fmaf(rB0, pg3b, pe3b);
    xA = xA >= 0.0f ? xA : 0.2f * xA; xB = xB >= 0.0f ? xB : 0.2f * xB;
    out[(r0 + 0) * 128 + lane] = xA; out[(r0 + 0) * 128 + 64 + lane] = xB;
    xA = fmaf(rA1, pg3a, pe3a); xB = fmaf(rB1, pg3b, pe3b);
    xA = xA >= 0.0f ? xA : 0.2f * xA; xB = xB >= 0.0f ? xB : 0.2f * xB;
    out[(r0 + 1) * 128 + lane] = xA; out[(r0 + 1) * 128 + 64 + lane] = xB;
    xA = fmaf(rA2, pg3a, pe3a); xB = fmaf(rB2, pg3b, pe3b);
    xA = xA >= 0.0f ? xA : 0.2f * xA; xB = xB >= 0.0f ? xB : 0.2f * xB;
    out[(r0 + 2) * 128 + lane] = xA; out[(r0 + 2) * 128 + 64 + lane] = xB;
    xA = fmaf(rA3, pg3a, pe3a); xB = fmaf(rB3, pg3b, pe3b);
    xA = xA >= 0.0f ? xA : 0.2f * xA; xB = xB >= 0.0f ? xB : 0.2f * xB;
    out[(r0 + 3) * 128 + lane] = xA; out[(r0 + 3) * 128 + 64 + lane] = xB;
  }
}

extern "C" void kernel_launch(void* const* d_in, const int* in_sizes, int n_in,
                              void* d_out, int out_size, void* d_ws, size_t ws_size,
                              hipStream_t stream) {
  const float* xyz  = (const float*)d_in[0];
  const float* feat = (const float*)d_in[1];
  const int*   smp  = (const int*)d_in[2];
  const float* w1   = (const float*)d_in[3];
  const float* b1   = (const float*)d_in[4];
  const float* g1   = (const float*)d_in[5];
  const float* be1  = (const float*)d_in[6];
  const float* w2   = (const float*)d_in[7];
  const float* b2   = (const float*)d_in[8];
  const float* g2   = (const float*)d_in[9];
  const float* be2  = (const float*)d_in[10];
  const float* w3   = (const float*)d_in[11];
  const float* b3   = (const float*)d_in[12];
  const float* g3   = (const float*)d_in[13];
  const float* be3  = (const float*)d_in[14];
  float* out = (float*)d_out;

  char* ws = (char*)d_ws;
  float4* P      = (float4*)(ws);                 // 262144 B
  float4* P2     = (float4*)(ws + 262144);        // 262144 B
  int*    idxMap = (int*)(ws + 524288);           // 65536 B
  float*  TR     = (float*)(ws + 589824);         // B*S*12*4 = 393216 B
  int*    AB     = (int*)(ws + 983040);           // 131072 B
  int*    AA     = (int*)(ws + 1114112);          // 131072 B

  pack_kernel<<<48, 512, 0, stream>>>(xyz, smp, P, P2, idxMap, out);
  knn_kernel<<<2048, 256, 0, stream>>>(P2, idxMap, TR, AB, AA);
  mlp_kernel<<<2048, 64, 0, stream>>>(TR, P, AB, AA, feat, smp,
                                      w1, b1, g1, be1, w2, b2, g2, be2,
                                      w3, b3, g3, be3, out + cB * cS * 3);
}